// Round 3
// baseline (179.507 us; speedup 1.0000x reference)
//
#include <hip/hip_runtime.h>
#include <hip/hip_bf16.h>

#define N_PTS 131072
#define CIN   32
#define COUT  32
#define KNB   27
#define NS    3
#define SEGS  128            // histogram segments of 1024 points
#define MAXBLK 4102          // 4096 + 6 (one partial block per bucket)

typedef __bf16 bf16x8 __attribute__((ext_vector_type(8)));
typedef float  f32x4  __attribute__((ext_vector_type(4)));

// Static device scratch (rewritten deterministically every call).
__device__ __attribute__((aligned(256))) __bf16 g_xT[2][N_PTS][32];      // [b][n][c]
__device__ __attribute__((aligned(256))) __bf16 g_wp[NS][KNB][32][32];   // [s][kc][o][c]
__device__ int g_hist[SEGS][6];
__device__ int g_woff[SEGS][6];
__device__ int g_entries[MAXBLK * 64];   // n | b<<17 | s<<18 | valid<<31

__device__ __forceinline__ int clip2(int v) { return v < 0 ? 0 : (v > 2 ? 2 : v); }

// ---------------- pack x: (B,CIN,N) f32 -> [b][n][c] bf16 ------------------
__global__ void pack_x(const float* __restrict__ x) {
  int n = blockIdx.x * 256 + threadIdx.x;
#pragma unroll
  for (int b = 0; b < 2; ++b) {
    uint u[16];
#pragma unroll
    for (int c = 0; c < 32; c += 2) {
      float f0 = x[(size_t)(b * 32 + c) * N_PTS + n];
      float f1 = x[(size_t)(b * 32 + c + 1) * N_PTS + n];
      union { __bf16 h[2]; uint w; } cv;
      cv.h[0] = (__bf16)f0; cv.h[1] = (__bf16)f1;
      u[c / 2] = cv.w;
    }
    uint4* dst = reinterpret_cast<uint4*>(&g_xT[b][n][0]);
#pragma unroll
    for (int i = 0; i < 4; ++i)
      dst[i] = make_uint4(u[4 * i], u[4 * i + 1], u[4 * i + 2], u[4 * i + 3]);
  }
}

// ------- pack w: (CIN,S,COUT,27) f32 -> [s][kc][o][c] bf16 -----------------
__global__ void pack_w(const float* __restrict__ w) {
  int e = blockIdx.x * 256 + threadIdx.x;   // 3*27*32*32 = 82944 = 324*256
  int c = e & 31;
  int o = (e >> 5) & 31;
  int r = e >> 10;            // s*27 + kc
  int kc = r % 27, s = r / 27;
  g_wp[s][kc][o][c] = (__bf16)w[((size_t)(c * NS + s) * COUT + o) * KNB + kc];
}

// ---------------- bucket histogram -----------------------------------------
__global__ void histo(const int* __restrict__ lv, const int* __restrict__ dlt) {
  __shared__ int h[6];
  int tid = threadIdx.x;
  if (tid < 6) h[tid] = 0;
  __syncthreads();
  int d0 = dlt[0], d1 = dlt[1];
  int base = blockIdx.x * 1024 + tid * 4;
#pragma unroll
  for (int i = 0; i < 4; ++i) {
    int l = lv[base + i];
    atomicAdd(&h[clip2(l + d0)], 1);
    atomicAdd(&h[3 + clip2(l + d1)], 1);
  }
  __syncthreads();
  if (tid < 6) g_hist[blockIdx.x][tid] = h[tid];
}

// ---------------- scan: bucket bases (padded to 64) + per-seg offsets ------
__global__ void scan() {
  __shared__ int tot[6], pb[7];
  int j = threadIdx.x;
  if (j < 6) { int t = 0; for (int b = 0; b < SEGS; ++b) t += g_hist[b][j]; tot[j] = t; }
  __syncthreads();
  if (j == 0) { int acc = 0; for (int q = 0; q < 6; ++q) { pb[q] = acc; acc += (tot[q] + 63) & ~63; } pb[6] = acc; }
  __syncthreads();
  if (j < 6) { int acc = pb[j]; for (int b = 0; b < SEGS; ++b) { g_woff[b][j] = acc; acc += g_hist[b][j]; } }
}

// ---------------- zero entries (padding = invalid) --------------------------
__global__ void zfill() {
  int i = blockIdx.x * 256 + threadIdx.x;
  if (i < MAXBLK * 64) g_entries[i] = 0;
}

// ---------------- ordered scatter into buckets ------------------------------
__global__ void scatter(const int* __restrict__ lv, const int* __restrict__ dlt) {
  __shared__ int sc[6][256];
  int tid = threadIdx.x, blk = blockIdx.x;
  int d0 = dlt[0], d1 = dlt[1];
  int base = blk * 1024 + tid * 4;
  int bj[8];
  int cnt[6] = {0, 0, 0, 0, 0, 0};
#pragma unroll
  for (int i = 0; i < 4; ++i) {
    int l = lv[base + i];
    bj[i * 2]     = clip2(l + d0);
    bj[i * 2 + 1] = 3 + clip2(l + d1);
#pragma unroll
    for (int j = 0; j < 6; ++j) { cnt[j] += (bj[i * 2] == j); cnt[j] += (bj[i * 2 + 1] == j); }
  }
#pragma unroll
  for (int j = 0; j < 6; ++j) sc[j][tid] = cnt[j];
  __syncthreads();
  for (int off = 1; off < 256; off <<= 1) {
    int v[6];
#pragma unroll
    for (int j = 0; j < 6; ++j) v[j] = (tid >= off) ? sc[j][tid - off] : 0;
    __syncthreads();
#pragma unroll
    for (int j = 0; j < 6; ++j) sc[j][tid] += v[j];
    __syncthreads();
  }
  int pos[6];
#pragma unroll
  for (int j = 0; j < 6; ++j) pos[j] = g_woff[blk][j] + sc[j][tid] - cnt[j];
#pragma unroll
  for (int i = 0; i < 4; ++i)
#pragma unroll
    for (int b = 0; b < 2; ++b) {
      int j = bj[i * 2 + b];
      int n = base + i;
      int s = j - (b ? 3 : 0);
      int e = n | (b << 17) | (s << 18) | (int)0x80000000;
#pragma unroll
      for (int q = 0; q < 6; ++q)
        if (j == q) { g_entries[pos[q]] = e; pos[q]++; }
    }
}

// ---------------- main: 64 same-(b,s) slots per block -----------------------
__global__ __launch_bounds__(256, 2) void aprconv(
    const int* __restrict__ nbr, const float* __restrict__ bias,
    float* __restrict__ out) {

  __shared__ __attribute__((aligned(16))) __bf16 s_w[KNB * 32 * 40]; // 80B row stride, row=kc*32+o
  __shared__ int   s_ent[64];
  __shared__ int   s_idx[KNB * 64];      // [kc][slot]
  __shared__ float s_bias[COUT];

  const int tid = threadIdx.x;
  const int blk = blockIdx.x;

  if (tid < 64)   s_ent[tid]  = g_entries[blk * 64 + tid];
  if (tid < COUT) s_bias[tid] = bias[tid];
  __syncthreads();

  const int e0    = s_ent[0];
  const int s_sel = (e0 >> 18) & 3;
  const int b_sel = (e0 >> 17) & 1;

  // stage W[s_sel] (55296B contiguous) into 80B-padded LDS rows
  {
    const char* wsrc = (const char*)&g_wp[s_sel][0][0][0];
    char* wdst = (char*)s_w;
    for (int j = tid; j < 3456; j += 256) {
      int r = j >> 2, sg = j & 3;
      *(uint4*)(wdst + r * 80 + sg * 16) = *(const uint4*)(wsrc + r * 64 + sg * 16);
    }
  }
  // stage neighbor indices (read slot-major for coalescing, store kc-major)
  for (int j = tid; j < 64 * KNB; j += 256) {
    int slot = j / 27, kc = j - slot * 27;
    int n = s_ent[slot] & 0x1FFFF;
    s_idx[kc * 64 + slot] = nbr[(size_t)n * KNB + kc];
  }
  __syncthreads();

  const int wv = tid >> 6, l15 = tid & 15, lg = (tid & 63) >> 4;
  const int slot = wv * 16 + l15;
  const char* xbase = (const char*)&g_xT[b_sel][0][0];
  const char* wrow  = (const char*)s_w + l15 * 80 + lg * 16;

  f32x4 acc0 = {0.f, 0.f, 0.f, 0.f}, acc1 = {0.f, 0.f, 0.f, 0.f};

  // x-gather pipeline depth 3
  bf16x8 xa, xb, xc;
  {
    int i0 = s_idx[slot];
    int i1 = s_idx[64 + slot];
    int i2 = s_idx[128 + slot];
    xa = *(const bf16x8*)(xbase + ((uint)i0 << 6) + (lg << 4));
    xb = *(const bf16x8*)(xbase + ((uint)i1 << 6) + (lg << 4));
    xc = *(const bf16x8*)(xbase + ((uint)i2 << 6) + (lg << 4));
  }

#pragma unroll 3
  for (int kc = 0; kc < KNB; ++kc) {
    const int kn3 = (kc + 3 < KNB) ? kc + 3 : KNB - 1;
    int i3 = s_idx[kn3 * 64 + slot];
    bf16x8 xn = *(const bf16x8*)(xbase + ((uint)i3 << 6) + (lg << 4));

    bf16x8 w0 = *(const bf16x8*)(wrow + (kc * 32) * 80);
    bf16x8 w1 = *(const bf16x8*)(wrow + (kc * 32 + 16) * 80);

    acc0 = __builtin_amdgcn_mfma_f32_16x16x32_bf16(w0, xa, acc0, 0, 0, 0);
    acc1 = __builtin_amdgcn_mfma_f32_16x16x32_bf16(w1, xa, acc1, 0, 0, 0);

    xa = xb; xb = xc; xc = xn;
  }

  // epilogue: D col(point)=lane&15, row(o)=(lane>>4)*4+reg
  const int e = s_ent[slot];
  if (e < 0) {   // valid bit
    const int n = e & 0x1FFFF;
#pragma unroll
    for (int r = 0; r < 4; ++r) {
      int o0 = lg * 4 + r;
      out[(size_t)(b_sel * COUT + o0) * N_PTS + n]        = acc0[r] + s_bias[o0];
      out[(size_t)(b_sel * COUT + o0 + 16) * N_PTS + n]   = acc1[r] + s_bias[o0 + 16];
    }
  }
}

extern "C" void kernel_launch(void* const* d_in, const int* in_sizes, int n_in,
                              void* d_out, int out_size, void* d_ws, size_t ws_size,
                              hipStream_t stream) {
  const float* x    = (const float*)d_in[0];
  const float* w    = (const float*)d_in[1];
  const float* bias = (const float*)d_in[2];
  const int* nbr    = (const int*)d_in[3];
  const int* lv     = (const int*)d_in[4];
  const int* dlt    = (const int*)d_in[5];
  float* out        = (float*)d_out;

  hipLaunchKernelGGL(pack_x, dim3(N_PTS / 256), dim3(256), 0, stream, x);
  hipLaunchKernelGGL(pack_w, dim3((NS * KNB * 1024) / 256), dim3(256), 0, stream, w);
  hipLaunchKernelGGL(histo, dim3(SEGS), dim3(256), 0, stream, lv, dlt);
  hipLaunchKernelGGL(scan, dim3(1), dim3(64), 0, stream);
  hipLaunchKernelGGL(zfill, dim3((MAXBLK * 64 + 255) / 256), dim3(256), 0, stream);
  hipLaunchKernelGGL(scatter, dim3(SEGS), dim3(256), 0, stream, lv, dlt);
  hipLaunchKernelGGL(aprconv, dim3(MAXBLK), dim3(256), 0, stream, nbr, bias, out);
}

// Round 4
// 100.199 us; speedup vs baseline: 1.7915x; 1.7915x over previous
//
#include <hip/hip_runtime.h>
#include <hip/hip_bf16.h>

#define N_PTS 131072
#define KNB   27
#define KPAD  28
#define NSTEP 14

typedef __bf16 bf16x8 __attribute__((ext_vector_type(8)));
typedef float  f32x4  __attribute__((ext_vector_type(4)));

// Static device scratch (rewritten deterministically every call).
__device__ __attribute__((aligned(256))) __bf16 g_xT[(size_t)N_PTS * 64];  // [n][b][c]
__device__ __attribute__((aligned(256))) __bf16 g_wp[KPAD * 3072];         // [kc][r=s*2+ot][lg][o16][cj]

__device__ __forceinline__ void gld_lds16(const void* g, void* l) {
  __builtin_amdgcn_global_load_lds(
      (const __attribute__((address_space(1))) unsigned int*)g,
      (__attribute__((address_space(3))) unsigned int*)l, 16, 0, 0);
}

// ---------------- pack x: (B,CIN,N) f32 -> (N,B,CIN) bf16 (128B/point) ----
__global__ void pack_x(const float* __restrict__ x) {
  int n = blockIdx.x * 256 + threadIdx.x;
  uint u[32];
#pragma unroll
  for (int b = 0; b < 2; ++b)
#pragma unroll
    for (int c = 0; c < 32; c += 2) {
      float f0 = x[(size_t)(b * 32 + c) * N_PTS + n];
      float f1 = x[(size_t)(b * 32 + c + 1) * N_PTS + n];
      union { __bf16 h[2]; uint w; } cv;
      cv.h[0] = (__bf16)f0; cv.h[1] = (__bf16)f1;
      u[b * 16 + c / 2] = cv.w;
    }
  uint4* dst = reinterpret_cast<uint4*>(&g_xT[(size_t)n * 64]);
#pragma unroll
  for (int i = 0; i < 8; ++i)
    dst[i] = make_uint4(u[4 * i], u[4 * i + 1], u[4 * i + 2], u[4 * i + 3]);
}

// ---- pack w: (CIN,S,COUT,27) f32 -> [kc][r][lg][o16][cj] bf16, kc27=0 ----
__global__ void pack_w(const float* __restrict__ w) {
  int e = blockIdx.x * 256 + threadIdx.x;   // 28*3072 = 86016 = 336*256
  int kc = e / 3072;
  int q  = e - kc * 3072;
  int r  = q >> 9;            // s*2+ot
  int q2 = q & 511;
  int lg = q2 >> 7;
  int o16 = (q2 >> 3) & 15;
  int cj = q2 & 7;
  int s = r >> 1, ot = r & 1;
  int c = lg * 8 + cj, o = ot * 16 + o16;
  float v = (kc < KNB) ? w[((size_t)(c * 3 + s) * 32 + o) * KNB + kc] : 0.0f;
  g_wp[e] = (__bf16)v;
}

// ---------------- main: 64 points/block, counted-vmcnt W pipeline ----------
__global__ __launch_bounds__(256, 3) void aprconv(
    const int* __restrict__ nbr, const int* __restrict__ levels,
    const int* __restrict__ deltas, const float* __restrict__ bias,
    float* __restrict__ out) {

  __shared__ uint  s_w[3][3072];        // 3 bufs x 12KB (2 kc each)
  __shared__ int   s_idx[KPAD * 64];    // [kc][slot]
  __shared__ int   s_lv[64];
  __shared__ float s_bias[32];

  const int tid  = threadIdx.x;
  const int n0   = blockIdx.x * 64;
  const int wv   = tid >> 6;
  const int lane = tid & 63;
  const int l15  = tid & 15;
  const int lg   = lane >> 4;
  const int slot = wv * 16 + l15;

  for (int j = tid; j < 64 * KNB; j += 256) {
    int p = j / KNB, kc = j - p * KNB;
    s_idx[kc * 64 + p] = nbr[(size_t)(n0 + p) * KNB + kc];
  }
  if (tid < 64) {
    s_lv[tid] = levels[n0 + tid];
    s_idx[27 * 64 + tid] = nbr[(size_t)(n0 + tid) * KNB + 26];  // pad kc (W=0)
  }
  if (tid < 32) s_bias[tid] = bias[tid];
  const int d0 = deltas[0], d1 = deltas[1];
  __syncthreads();   // full drain: vmcnt FIFO empty past this point

  const char* xbase = (const char*)g_xT;
  const char* wsrc  = (const char*)g_wp;

#define STAGE(t) do { \
    const int _t = (t); \
    const char* _s = wsrc + _t * 12288 + (wv * 3) * 1024 + lane * 16; \
    char* _d = (char*)&s_w[_t % 3][0] + (wv * 3) * 1024; \
    gld_lds16(_s,        _d); \
    gld_lds16(_s + 1024, _d + 1024); \
    gld_lds16(_s + 2048, _d + 2048); \
  } while (0)

#define GATHER(t, dst) do { \
    const int _t = (t); \
    const uint _i0 = (uint)s_idx[(_t * 2) * 64 + slot]; \
    const uint _i1 = (uint)s_idx[(_t * 2 + 1) * 64 + slot]; \
    const char* _p0 = xbase + (_i0 << 7) + (lg << 4); \
    const char* _p1 = xbase + (_i1 << 7) + (lg << 4); \
    dst[0] = *(const bf16x8*)_p0; \
    dst[1] = *(const bf16x8*)(_p0 + 64); \
    dst[2] = *(const bf16x8*)_p1; \
    dst[3] = *(const bf16x8*)(_p1 + 64); \
  } while (0)

  f32x4 acc[2][3][2];
#pragma unroll
  for (int b = 0; b < 2; ++b)
#pragma unroll
    for (int s = 0; s < 3; ++s)
#pragma unroll
      for (int ot = 0; ot < 2; ++ot)
        acc[b][s][ot] = (f32x4){0.f, 0.f, 0.f, 0.f};

  bf16x8 xa[4], xb[4], xc[4];

  // prologue: FIFO = [W0:3, W1:3, x0:4, x1:4] = 14; drain W0 -> keep 11
  STAGE(0); STAGE(1);
  __builtin_amdgcn_sched_barrier(0);
  GATHER(0, xa); GATHER(1, xb);
  asm volatile("s_waitcnt vmcnt(11)" ::: "memory");
  __builtin_amdgcn_s_barrier();
  __builtin_amdgcn_sched_barrier(0);

#pragma unroll
  for (int st = 0; st < NSTEP; ++st) {
    const int tn = (st + 2 < NSTEP) ? st + 2 : NSTEP - 1;

    STAGE(tn);                                 // W(st+2) -> buf[(st+2)%3]
    __builtin_amdgcn_sched_barrier(0);         // pin issue order (vmcnt count!)
    GATHER(tn, xc);                            // x(st+2) -> regs
    // FIFO: [x(st):4, W(st+1):3, x(st+1):4, W(st+2):3, x(st+2):4]=18
    // keep 11 -> drains x(st) (for MFMA now) + W(st+1) (for next body's ds_read)
    asm volatile("s_waitcnt vmcnt(11)" ::: "memory");
    __builtin_amdgcn_sched_barrier(0);

    const char* wbuf = (const char*)&s_w[st % 3][0];
#pragma unroll
    for (int k2 = 0; k2 < 2; ++k2) {
      bf16x8 wf[6];
#pragma unroll
      for (int r = 0; r < 6; ++r)
        wf[r] = *(const bf16x8*)(wbuf + k2 * 6144 + r * 1024 + (lg << 8) + (l15 << 4));
#pragma unroll
      for (int s3 = 0; s3 < 3; ++s3)
#pragma unroll
        for (int ot = 0; ot < 2; ++ot) {
          acc[0][s3][ot] = __builtin_amdgcn_mfma_f32_16x16x32_bf16(wf[s3 * 2 + ot], xa[k2 * 2 + 0], acc[0][s3][ot], 0, 0, 0);
          acc[1][s3][ot] = __builtin_amdgcn_mfma_f32_16x16x32_bf16(wf[s3 * 2 + ot], xa[k2 * 2 + 1], acc[1][s3][ot], 0, 0, 0);
        }
    }

#pragma unroll
    for (int q = 0; q < 4; ++q) { xa[q] = xb[q]; xb[q] = xc[q]; }

    asm volatile("s_waitcnt lgkmcnt(0)" ::: "memory");  // ds_reads done pre-barrier
    __builtin_amdgcn_s_barrier();
    __builtin_amdgcn_sched_barrier(0);
  }

#undef STAGE
#undef GATHER

  // epilogue: per-point s select + bias + coalesced store
  // D layout: col(point)=lane&15, row(o within 16)=(lane>>4)*4+reg
  const int lv = s_lv[slot];
  int e0 = lv + d0; e0 = e0 < 0 ? 0 : (e0 > 2 ? 2 : e0);
  int e1 = lv + d1; e1 = e1 < 0 ? 0 : (e1 > 2 ? 2 : e1);
  const int n = n0 + slot;
#pragma unroll
  for (int b = 0; b < 2; ++b) {
    const int sb = b ? e1 : e0;
#pragma unroll
    for (int ot = 0; ot < 2; ++ot) {
      f32x4 a0 = acc[b][0][ot], a1 = acc[b][1][ot], a2 = acc[b][2][ot];
      f32x4 v;
#pragma unroll
      for (int r = 0; r < 4; ++r)
        v[r] = (sb == 0) ? a0[r] : ((sb == 1) ? a1[r] : a2[r]);
#pragma unroll
      for (int r = 0; r < 4; ++r) {
        int o = ot * 16 + lg * 4 + r;
        out[(size_t)(b * 32 + o) * N_PTS + n] = v[r] + s_bias[o];
      }
    }
  }
}

extern "C" void kernel_launch(void* const* d_in, const int* in_sizes, int n_in,
                              void* d_out, int out_size, void* d_ws, size_t ws_size,
                              hipStream_t stream) {
  const float* x    = (const float*)d_in[0];
  const float* w    = (const float*)d_in[1];
  const float* bias = (const float*)d_in[2];
  const int* nbr    = (const int*)d_in[3];
  const int* lv     = (const int*)d_in[4];
  const int* dlt    = (const int*)d_in[5];
  float* out        = (float*)d_out;

  hipLaunchKernelGGL(pack_x, dim3(N_PTS / 256), dim3(256), 0, stream, x);
  hipLaunchKernelGGL(pack_w, dim3((KPAD * 3072) / 256), dim3(256), 0, stream, w);
  hipLaunchKernelGGL(aprconv, dim3(N_PTS / 64), dim3(256), 0, stream, nbr, lv, dlt, bias, out);
}